// Round 8
// baseline (289.869 us; speedup 1.0000x reference)
//
#include <hip/hip_runtime.h>

#define Hh 160
#define Ww 160
#define HW 25600
#define Bb 8
#define Cc 64
#define Oo 64
#define NPIX (Bb * HW)   // 204800

#define TROWS 8
#define TCOLS 36
#define TPIX (TROWS * TCOLS)   // 288 pixel-rows in the LDS tile

typedef __bf16 bf16x8 __attribute__((ext_vector_type(8)));
typedef float  f32x4  __attribute__((ext_vector_type(4)));
typedef float  f32x2  __attribute__((ext_vector_type(2)));

__device__ inline unsigned rnd_bf(float a) {
    unsigned u = __float_as_uint(a);
    return (u + 0x7FFFu + ((u >> 16) & 1u)) >> 16;   // RNE f32->bf16 (prep only)
}
// RNE pack of two f32 -> packed bf16x2 in ONE instruction (lo = a, hi = b)
__device__ inline unsigned cvtpk(float a, float b) {
    unsigned r;
    asm("v_cvt_pk_bf16_f32 %0, %1, %2" : "=v"(r) : "v"(a), "v"(b));
    return r;
}
__device__ inline f32x2 up2(unsigned u) {
    f32x2 r;
    r.x = __uint_as_float(u << 16);
    r.y = __uint_as_float(u & 0xffff0000u);
    return r;
}
__device__ inline unsigned blend4(unsigned u00, unsigned u01, unsigned u10, unsigned u11,
                                  float w00, float w01, float w10, float w11) {
    f32x2 r = up2(u00) * w00 + up2(u01) * w01 + up2(u10) * w10 + up2(u11) * w11;
    return cvtpk(r.x, r.y);
}
union UV { uint4 u; bf16x8 v; };
__device__ inline bf16x8 as_bf(uint4 u) { UV c; c.u = u; return c.v; }

// ---- prep: fragment-major weights so dcn's B-loads are contiguous 1KB/wave ----
__global__ __launch_bounds__(256) void prep_kernel(
    const float* __restrict__ w_dcn, const float* __restrict__ b_dcn,
    const float* __restrict__ w_off,
    const float* __restrict__ gamma, const float* __restrict__ beta,
    const float* __restrict__ run_mean, const float* __restrict__ run_var,
    unsigned short* __restrict__ wtbf, unsigned short* __restrict__ wofbf,
    float* __restrict__ scaleb)
{
    int i = blockIdx.x * 256 + threadIdx.x;
    if (i < 9 * 8 * 64 * 8) {              // 36864
        int j = i & 7, l = (i >> 3) & 63, f = (i >> 9) & 7, k = i >> 12;
        int o  = ((f >> 1) << 4) | (l & 15);
        int cc = ((l >> 4) << 3) + ((f & 1) << 5) + j;
        wtbf[i] = (unsigned short)rnd_bf(w_dcn[(o * Cc + cc) * 9 + k]);
    }
    if (i < 9 * 4 * 64 * 8) {              // 18432
        int j = i & 7, l = (i >> 3) & 63, f = (i >> 9) & 3, k = i >> 11;
        int o  = ((f >> 1) << 4) | (l & 15);
        int cc = ((l >> 4) << 3) + ((f & 1) << 5) + j;
        float v = (o < 18) ? w_off[(o * Cc + cc) * 9 + k] : 0.0f;
        wofbf[i] = (unsigned short)rnd_bf(v);
    }
    if (i < Oo) {
        float inv = gamma[i] * rsqrtf(run_var[i] + 1e-5f);
        scaleb[i]      = inv;
        scaleb[Oo + i] = b_dcn[i] * inv + (beta[i] - run_mean[i] * inv);
    }
}

// swizzled tile read: pixel-row PIX, this lane's two 16B chunks (quad, quad+4)
#define TRD(PIX, LO, HI) do {                                                  \
    int _pp = (PIX);                                                           \
    int _s  = _pp & 7;                                                         \
    const char* _tb = (const char*)tile + _pp * 128;                           \
    LO = *(const uint4*)(_tb + ((quad ^ _s) << 4));                            \
    HI = *(const uint4*)(_tb + (((quad + 4) ^ _s) << 4));                      \
} while (0)

// rare out-of-window gather straight from NCHW x (same RNE conversion as tile)
#define GATHF(CY, CX, A, H) do {                                               \
    const float* _sp = xbf + (size_t)(quad * 8) * HW + ((CY) * Ww + (CX));     \
    A = make_uint4(cvtpk(_sp[0],      _sp[HW]),                                \
                   cvtpk(_sp[2 * HW], _sp[3 * HW]),                            \
                   cvtpk(_sp[4 * HW], _sp[5 * HW]),                            \
                   cvtpk(_sp[6 * HW], _sp[7 * HW]));                           \
    const float* _hp = _sp + (size_t)32 * HW;                                  \
    H = make_uint4(cvtpk(_hp[0],      _hp[HW]),                                \
                   cvtpk(_hp[2 * HW], _hp[3 * HW]),                            \
                   cvtpk(_hp[4 * HW], _hp[5 * HW]),                            \
                   cvtpk(_hp[6 * HW], _hp[7 * HW]));                           \
} while (0)

// ---- fused: offset-conv(MFMA) + deform-sample + projection(MFMA) + BN + ReLU --
// v8: offb LDS is GONE. Phase-1 uses the operand-SWAP trick: A and B fragments
// of mfma_16x16x32 have identical lane layouts (idx=lane&15, k=quad*8+j), so
// mfma(weights, pixels, acc) flips the accumulator to D[o=quad*4+r][px=m] —
// each lane holds channels of ITS OWN pixel; the 18 offsets are collected with
// 18 compile-time __shfl's (no LDS transpose). LDS = tile only (36864 B) ->
// 4 blocks/CU = 32-wave cap (was 24). Epilogue store remapped so 8 consecutive
// lanes cover one aligned 128B line (v7 still had 2x write amplification from
// 64B-strided lanes within each store instruction). pack_bf2 (3 ops) replaced
// by v_cvt_pk_bf16_f32 (1 op, RNE) in blend/staging/fallback.
__global__ __launch_bounds__(512, 8) void dcn_kernel(
    const float* __restrict__ x,
    const unsigned short* __restrict__ wtbf,    // [9][8][64][8]
    const unsigned short* __restrict__ wofbf,   // [9][4][64][8]
    const float* __restrict__ b_off,
    const float* __restrict__ scaleb,
    float* __restrict__ out)
{
    __shared__ __align__(16) unsigned short tile[TPIX * 64];  // 36864 B total

    const int t = threadIdx.x;
    const int lane = t & 63, wv = t >> 6;      // wv 0..7
    const int m = lane & 15, quad = lane >> 4;

    int blk = blockIdx.x;                      // 1600
    int b   = blk & 7;                         // XCD swizzle: 1 image/XCD
    int nb  = blk >> 3;                        // 0..199
    int h0  = (nb / 5) * 4;                    // 4-row group
    int w0  = (nb % 5) * 32;                   // 32-px segment, row-aligned

    const int rloc  = wv >> 1;                 // wave's output row (0..3)
    const int chalf = (wv & 1) * 16;           // wave's col half
    const int h = h0 + rloc;
    const int w = w0 + chalf + m;              // this lane's pixel col
    const int pl_base = rloc * 32 + chalf;     // wave's first pixel id (0..127)

    const float* xbf = x + (size_t)b * Cc * HW;

    // ---- stage tile from NCHW x: transpose + bf16 pack, coalesced along w ----
#pragma unroll
    for (int it = 0; it < 18; ++it) {
        int id  = t + it * 512;
        int col = id % 36;
        int rr  = id / 36;                 // c2*8 + r
        int r   = rr & 7;
        int c2  = rr >> 3;                 // channel pair 0..31
        int yr = min(max(h0 - 2 + r, 0), Hh - 1);
        int xc = min(max(w0 - 2 + col, 0), Ww - 1);
        const float* sp = xbf + (size_t)(c2 * 2) * HW + (yr * Ww + xc);
        unsigned v = cvtpk(sp[0], sp[HW]);
        int pix = r * TCOLS + col;
        *(unsigned*)((char*)tile + pix * 128
                     + ((((c2 >> 2) ^ (pix & 7)) << 4) + ((c2 & 3) << 2))) = v;
    }
    __syncthreads();

    // ===== phase 1: offset conv, SWAPPED operands: D[o=quad*4+r][px=m] ========
    f32x4 oa0 = {0,0,0,0}, oa1 = {0,0,0,0};
#pragma unroll
    for (int k = 0; k < 9; ++k) {
        int hp = h + k / 3 - 1, wp = w + (k % 3) - 1;
        bool ok = (hp >= 0) & (hp < Hh) & (wp >= 0) & (wp < Ww);
        int r = min(max(hp, 0), Hh - 1) - h0 + 2;      // in [0,7]
        int c = min(max(wp, 0), Ww - 1) - w0 + 2;      // in [0,35]
        uint4 r0, r1;
        TRD(r * TCOLS + c, r0, r1);
        if (!ok) { r0 = make_uint4(0,0,0,0); r1 = make_uint4(0,0,0,0); }
        bf16x8 a0 = as_bf(r0), a1 = as_bf(r1);

        const unsigned short* wf = wofbf + (size_t)(k * 4) * 512 + lane * 8;
        bf16x8 b00 = *(const bf16x8*)(wf);
        bf16x8 b01 = *(const bf16x8*)(wf + 512);
        bf16x8 b10 = *(const bf16x8*)(wf + 1024);
        bf16x8 b11 = *(const bf16x8*)(wf + 1536);
        // weights as A-operand, pixels as B-operand (fragments are layout-identical)
        oa0 = __builtin_amdgcn_mfma_f32_16x16x32_bf16(b00, a0, oa0, 0, 0, 0);
        oa0 = __builtin_amdgcn_mfma_f32_16x16x32_bf16(b01, a1, oa0, 0, 0, 0);
        oa1 = __builtin_amdgcn_mfma_f32_16x16x32_bf16(b10, a0, oa1, 0, 0, 0);
        oa1 = __builtin_amdgcn_mfma_f32_16x16x32_bf16(b11, a1, oa1, 0, 0, 0);
    }

    // offsets: lane (m,quad) holds ch quad*4+r (oa0) / 16+quad*4+r (oa1) of
    // pixel m. Gather all 18 channels of OWN pixel via compile-time shuffles.
    float oy[9], ox[9];
#pragma unroll
    for (int k = 0; k < 9; ++k) {
        int cy = 2 * k, cx = 2 * k + 1;
        float vy = (cy < 16) ? __shfl(oa0[cy & 3], ((cy >> 2) << 4) + m, 64)
                             : __shfl(oa1[(cy - 16) & 3], (((cy - 16) >> 2) << 4) + m, 64);
        float vx = (cx < 16) ? __shfl(oa0[cx & 3], ((cx >> 2) << 4) + m, 64)
                             : __shfl(oa1[(cx - 16) & 3], (((cx - 16) >> 2) << 4) + m, 64);
        oy[k] = vy + b_off[cy];
        ox[k] = vx + b_off[cx];
    }

    // ================= phase 2: deform sample (tile) + projection ==============
    f32x4 c0 = {0,0,0,0}, c1 = {0,0,0,0}, c2 = {0,0,0,0}, c3 = {0,0,0,0};
#pragma unroll
    for (int k = 0; k < 9; ++k) {
        float py = (float)(h + k / 3 - 1) + oy[k];
        float px = (float)(w + k % 3 - 1) + ox[k];
        float y0f = floorf(py), x0f = floorf(px);
        float fy = py - y0f, fx = px - x0f;
        int y0 = (int)y0f, x0i = (int)x0f;
        int y1 = y0 + 1, x1 = x0i + 1;
        bool vy0 = (y0 >= 0) & (y0 < Hh), vy1 = (y1 >= 0) & (y1 < Hh);
        bool vx0 = (x0i >= 0) & (x0i < Ww), vx1 = (x1 >= 0) & (x1 < Ww);
        float w00 = (vy0 & vx0) ? (1.0f - fy) * (1.0f - fx) : 0.0f;
        float w01 = (vy0 & vx1) ? (1.0f - fy) * fx : 0.0f;
        float w10 = (vy1 & vx0) ? fy * (1.0f - fx) : 0.0f;
        float w11 = (vy1 & vx1) ? fy * fx : 0.0f;
        int cy0 = min(max(y0, 0), Hh - 1), cy1 = min(max(y1, 0), Hh - 1);
        int cx0 = min(max(x0i, 0), Ww - 1), cx1 = min(max(x1, 0), Ww - 1);

        int r0 = cy0 - h0 + 2, r1 = cy1 - h0 + 2;      // tile coords
        int d0 = cx0 - w0 + 2, d1 = cx1 - w0 + 2;
        int inw = ((unsigned)r0 <= 7u) & ((unsigned)r1 <= 7u) &
                  ((unsigned)d0 <= 35u) & ((unsigned)d1 <= 35u);

        uint4 a00, h00, a01, h01, a10, h10, a11, h11;
        if (__all(inw)) {                              // fast path: LDS tile
            TRD(r0 * TCOLS + d0, a00, h00);
            TRD(r0 * TCOLS + d1, a01, h01);
            TRD(r1 * TCOLS + d0, a10, h10);
            TRD(r1 * TCOLS + d1, a11, h11);
        } else {                                       // rare: global gathers
            GATHF(cy0, cx0, a00, h00);
            GATHF(cy0, cx1, a01, h01);
            GATHF(cy1, cx0, a10, h10);
            GATHF(cy1, cx1, a11, h11);
        }

        uint4 o0, o1;
        o0.x = blend4(a00.x, a01.x, a10.x, a11.x, w00, w01, w10, w11);
        o0.y = blend4(a00.y, a01.y, a10.y, a11.y, w00, w01, w10, w11);
        o0.z = blend4(a00.z, a01.z, a10.z, a11.z, w00, w01, w10, w11);
        o0.w = blend4(a00.w, a01.w, a10.w, a11.w, w00, w01, w10, w11);
        o1.x = blend4(h00.x, h01.x, h10.x, h11.x, w00, w01, w10, w11);
        o1.y = blend4(h00.y, h01.y, h10.y, h11.y, w00, w01, w10, w11);
        o1.z = blend4(h00.z, h01.z, h10.z, h11.z, w00, w01, w10, w11);
        o1.w = blend4(h00.w, h01.w, h10.w, h11.w, w00, w01, w10, w11);
        bf16x8 A0 = as_bf(o0), A1 = as_bf(o1);

        const unsigned short* wf = wtbf + (size_t)(k * 8) * 512 + lane * 8;
        bf16x8 B0, B1;
        B0 = *(const bf16x8*)(wf);
        B1 = *(const bf16x8*)(wf + 512);
        c0 = __builtin_amdgcn_mfma_f32_16x16x32_bf16(A0, B0, c0, 0, 0, 0);
        c0 = __builtin_amdgcn_mfma_f32_16x16x32_bf16(A1, B1, c0, 0, 0, 0);
        B0 = *(const bf16x8*)(wf + 1024);
        B1 = *(const bf16x8*)(wf + 1536);
        c1 = __builtin_amdgcn_mfma_f32_16x16x32_bf16(A0, B0, c1, 0, 0, 0);
        c1 = __builtin_amdgcn_mfma_f32_16x16x32_bf16(A1, B1, c1, 0, 0, 0);
        B0 = *(const bf16x8*)(wf + 2048);
        B1 = *(const bf16x8*)(wf + 2560);
        c2 = __builtin_amdgcn_mfma_f32_16x16x32_bf16(A0, B0, c2, 0, 0, 0);
        c2 = __builtin_amdgcn_mfma_f32_16x16x32_bf16(A1, B1, c2, 0, 0, 0);
        B0 = *(const bf16x8*)(wf + 3072);
        B1 = *(const bf16x8*)(wf + 3584);
        c3 = __builtin_amdgcn_mfma_f32_16x16x32_bf16(A0, B0, c3, 0, 0, 0);
        c3 = __builtin_amdgcn_mfma_f32_16x16x32_bf16(A1, B1, c3, 0, 0, 0);
    }

    // ---- epilogue: BN+ReLU in regs, LDS re-layout, full-128B-line stores ----
    __syncthreads();                       // all tile reads done; reuse as obuf
    float* obuf = (float*)tile;            // [o][132] floats = 33792 B <= 36864
#pragma unroll
    for (int nt = 0; nt < 4; ++nt) {
        f32x4 a = (nt == 0) ? c0 : (nt == 1) ? c1 : (nt == 2) ? c2 : c3;
        int o = nt * 16 + m;
        float sc = scaleb[o];
        float bs = scaleb[Oo + o];
        f32x4 r;
        r[0] = fmaxf(a[0] * sc + bs, 0.0f);
        r[1] = fmaxf(a[1] * sc + bs, 0.0f);
        r[2] = fmaxf(a[2] * sc + bs, 0.0f);
        r[3] = fmaxf(a[3] * sc + bs, 0.0f);
        *(f32x4*)&obuf[o * 132 + pl_base + quad * 4] = r;
    }
    __syncthreads();
    {
        // 8 consecutive lanes = one (o, row) 128B line, fully covered per instr
        int o = t >> 3, c8 = t & 7;
        const float* src = obuf + o * 132 + c8 * 4;
        float* dst = out + ((size_t)b * Oo + o) * HW + h0 * Ww + w0 + c8 * 4;
#pragma unroll
        for (int j = 0; j < 4; ++j) {
            float4 v = *(const float4*)(src + j * 32);
            *(float4*)(dst + (size_t)j * Ww) = v;
        }
    }
}

extern "C" void kernel_launch(void* const* d_in, const int* in_sizes, int n_in,
                              void* d_out, int out_size, void* d_ws, size_t ws_size,
                              hipStream_t stream) {
    const float* x        = (const float*)d_in[0];
    const float* w_off    = (const float*)d_in[1];
    const float* b_off    = (const float*)d_in[2];
    const float* w_dcn    = (const float*)d_in[3];
    const float* b_dcn    = (const float*)d_in[4];
    const float* gamma    = (const float*)d_in[5];
    const float* beta     = (const float*)d_in[6];
    const float* run_mean = (const float*)d_in[7];
    const float* run_var  = (const float*)d_in[8];
    float* out = (float*)d_out;

    // workspace: wtbf | wofbf | scaleb
    unsigned short* wtbf  = (unsigned short*)d_ws;        // 9*8*64*8 bf16
    unsigned short* wofbf = wtbf + 9 * 8 * 64 * 8;        // 9*4*64*8 bf16
    float* scaleb         = (float*)(wofbf + 9 * 4 * 64 * 8);  // 128 floats

    prep_kernel<<<(9 * 8 * 64 * 8 + 255) / 256, 256, 0, stream>>>(
        w_dcn, b_dcn, w_off, gamma, beta, run_mean, run_var, wtbf, wofbf, scaleb);

    dcn_kernel<<<NPIX / 128, 512, 0, stream>>>(x, wtbf, wofbf, b_off, scaleb, out);
}

// Round 9
// 201.785 us; speedup vs baseline: 1.4365x; 1.4365x over previous
//
#include <hip/hip_runtime.h>

#define Hh 160
#define Ww 160
#define HW 25600
#define Bb 8
#define Cc 64
#define Oo 64
#define NPIX (Bb * HW)   // 204800

#define TROWS 8
#define TCOLS 36
#define TPIX (TROWS * TCOLS)   // 288 pixel-rows in the LDS tile

typedef __bf16 bf16x8 __attribute__((ext_vector_type(8)));
typedef float  f32x4  __attribute__((ext_vector_type(4)));
typedef float  f32x2  __attribute__((ext_vector_type(2)));

__device__ inline unsigned rnd_bf(float a) {
    unsigned u = __float_as_uint(a);
    return (u + 0x7FFFu + ((u >> 16) & 1u)) >> 16;   // RNE f32->bf16 (prep only)
}
// RNE pack of two f32 -> packed bf16x2 in ONE instruction (lo = a, hi = b)
__device__ inline unsigned cvtpk(float a, float b) {
    unsigned r;
    asm("v_cvt_pk_bf16_f32 %0, %1, %2" : "=v"(r) : "v"(a), "v"(b));
    return r;
}
__device__ inline f32x2 up2(unsigned u) {
    f32x2 r;
    r.x = __uint_as_float(u << 16);
    r.y = __uint_as_float(u & 0xffff0000u);
    return r;
}
__device__ inline unsigned blend4(unsigned u00, unsigned u01, unsigned u10, unsigned u11,
                                  float w00, float w01, float w10, float w11) {
    f32x2 r = up2(u00) * w00 + up2(u01) * w01 + up2(u10) * w10 + up2(u11) * w11;
    return cvtpk(r.x, r.y);
}
union UV { uint4 u; bf16x8 v; };
__device__ inline bf16x8 as_bf(uint4 u) { UV c; c.u = u; return c.v; }

// ---- prep: fragment-major weights so dcn's B-loads are contiguous 1KB/wave ----
__global__ __launch_bounds__(256) void prep_kernel(
    const float* __restrict__ w_dcn, const float* __restrict__ b_dcn,
    const float* __restrict__ w_off,
    const float* __restrict__ gamma, const float* __restrict__ beta,
    const float* __restrict__ run_mean, const float* __restrict__ run_var,
    unsigned short* __restrict__ wtbf, unsigned short* __restrict__ wofbf,
    float* __restrict__ scaleb)
{
    int i = blockIdx.x * 256 + threadIdx.x;
    if (i < 9 * 8 * 64 * 8) {              // 36864
        int j = i & 7, l = (i >> 3) & 63, f = (i >> 9) & 7, k = i >> 12;
        int o  = ((f >> 1) << 4) | (l & 15);
        int cc = ((l >> 4) << 3) + ((f & 1) << 5) + j;
        wtbf[i] = (unsigned short)rnd_bf(w_dcn[(o * Cc + cc) * 9 + k]);
    }
    if (i < 9 * 4 * 64 * 8) {              // 18432
        int j = i & 7, l = (i >> 3) & 63, f = (i >> 9) & 3, k = i >> 11;
        int o  = ((f >> 1) << 4) | (l & 15);
        int cc = ((l >> 4) << 3) + ((f & 1) << 5) + j;
        float v = (o < 18) ? w_off[(o * Cc + cc) * 9 + k] : 0.0f;
        wofbf[i] = (unsigned short)rnd_bf(v);
    }
    if (i < Oo) {
        float inv = gamma[i] * rsqrtf(run_var[i] + 1e-5f);
        scaleb[i]      = inv;
        scaleb[Oo + i] = b_dcn[i] * inv + (beta[i] - run_mean[i] * inv);
    }
}

// swizzled tile read: pixel-row PIX, this lane's two 16B chunks (quad, quad+4)
#define TRD(PIX, LO, HI) do {                                                  \
    int _pp = (PIX);                                                           \
    int _s  = _pp & 7;                                                         \
    const char* _tb = (const char*)tile + _pp * 128;                           \
    LO = *(const uint4*)(_tb + ((quad ^ _s) << 4));                            \
    HI = *(const uint4*)(_tb + (((quad + 4) ^ _s) << 4));                      \
} while (0)

// rare out-of-window gather straight from NCHW x (same RNE conversion as tile)
#define GATHF(CY, CX, A, H) do {                                               \
    const float* _sp = xbf + (size_t)(quad * 8) * HW + ((CY) * Ww + (CX));     \
    A = make_uint4(cvtpk(_sp[0],      _sp[HW]),                                \
                   cvtpk(_sp[2 * HW], _sp[3 * HW]),                            \
                   cvtpk(_sp[4 * HW], _sp[5 * HW]),                            \
                   cvtpk(_sp[6 * HW], _sp[7 * HW]));                           \
    const float* _hp = _sp + (size_t)32 * HW;                                  \
    H = make_uint4(cvtpk(_hp[0],      _hp[HW]),                                \
                   cvtpk(_hp[2 * HW], _hp[3 * HW]),                            \
                   cvtpk(_hp[4 * HW], _hp[5 * HW]),                            \
                   cvtpk(_hp[6 * HW], _hp[7 * HW]));                           \
} while (0)

// ---- fused: offset-conv(MFMA) + deform-sample + projection(MFMA) + BN + ReLU --
// v9 = v7 (proven 122us dcn) + the two occupancy-neutral v8 deltas:
//  (1) full-128B-line epilogue: 8 CONSECUTIVE lanes cover one aligned line
//      (v7's reader interleaved 16B chunks at 64B stride -> 2x write amp);
//  (2) v_cvt_pk_bf16_f32 (1 op, RNE) replaces 3-op pack in stage/blend/fallback.
// v8's (512,8) hard-capped the unified VGPR+AGPR file at 64/wave -> massive
// scratch spill (+300 MB HBM). Reverted to (512,6); offb LDS transpose is back.
__global__ __launch_bounds__(512, 6) void dcn_kernel(
    const float* __restrict__ x,
    const unsigned short* __restrict__ wtbf,    // [9][8][64][8]
    const unsigned short* __restrict__ wofbf,   // [9][4][64][8]
    const float* __restrict__ b_off,
    const float* __restrict__ scaleb,
    float* __restrict__ out)
{
    __shared__ __align__(16) unsigned short tile[TPIX * 64];  // 36864 B
    __shared__ __align__(16) float offb[128 * 20];            // 10240 B (47104)

    const int t = threadIdx.x;
    const int lane = t & 63, wv = t >> 6;      // wv 0..7
    const int m = lane & 15, quad = lane >> 4;

    int blk = blockIdx.x;                      // 1600
    int b   = blk & 7;                         // XCD swizzle: 1 image/XCD
    int nb  = blk >> 3;                        // 0..199
    int h0  = (nb / 5) * 4;                    // 4-row group
    int w0  = (nb % 5) * 32;                   // 32-px segment, row-aligned

    const int rloc  = wv >> 1;                 // wave's output row (0..3)
    const int chalf = (wv & 1) * 16;           // wave's col half
    const int h = h0 + rloc;
    const int w = w0 + chalf + m;              // this lane's pixel col
    const int pl_base = rloc * 32 + chalf;     // wave's first pixel id (0..127)

    const float* xbf = x + (size_t)b * Cc * HW;

    // ---- stage tile from NCHW x: transpose + bf16 pack, coalesced along w ----
#pragma unroll
    for (int it = 0; it < 18; ++it) {
        int id  = t + it * 512;
        int col = id % 36;
        int rr  = id / 36;                 // c2*8 + r
        int r   = rr & 7;
        int c2  = rr >> 3;                 // channel pair 0..31
        int yr = min(max(h0 - 2 + r, 0), Hh - 1);
        int xc = min(max(w0 - 2 + col, 0), Ww - 1);
        const float* sp = xbf + (size_t)(c2 * 2) * HW + (yr * Ww + xc);
        unsigned v = cvtpk(sp[0], sp[HW]);
        int pix = r * TCOLS + col;
        *(unsigned*)((char*)tile + pix * 128
                     + ((((c2 >> 2) ^ (pix & 7)) << 4) + ((c2 & 3) << 2))) = v;
    }
    __syncthreads();

    // ================= phase 1: offset conv (A from tile, B global) ============
    f32x4 oa0 = {0,0,0,0}, oa1 = {0,0,0,0};
#pragma unroll
    for (int k = 0; k < 9; ++k) {
        int hp = h + k / 3 - 1, wp = w + (k % 3) - 1;
        bool ok = (hp >= 0) & (hp < Hh) & (wp >= 0) & (wp < Ww);
        int r = min(max(hp, 0), Hh - 1) - h0 + 2;      // in [0,7]
        int c = min(max(wp, 0), Ww - 1) - w0 + 2;      // in [0,35]
        uint4 r0, r1;
        TRD(r * TCOLS + c, r0, r1);
        if (!ok) { r0 = make_uint4(0,0,0,0); r1 = make_uint4(0,0,0,0); }
        bf16x8 a0 = as_bf(r0), a1 = as_bf(r1);

        const unsigned short* wf = wofbf + (size_t)(k * 4) * 512 + lane * 8;
        bf16x8 b00 = *(const bf16x8*)(wf);
        bf16x8 b01 = *(const bf16x8*)(wf + 512);
        bf16x8 b10 = *(const bf16x8*)(wf + 1024);
        bf16x8 b11 = *(const bf16x8*)(wf + 1536);
        oa0 = __builtin_amdgcn_mfma_f32_16x16x32_bf16(a0, b00, oa0, 0, 0, 0);
        oa0 = __builtin_amdgcn_mfma_f32_16x16x32_bf16(a1, b01, oa0, 0, 0, 0);
        oa1 = __builtin_amdgcn_mfma_f32_16x16x32_bf16(a0, b10, oa1, 0, 0, 0);
        oa1 = __builtin_amdgcn_mfma_f32_16x16x32_bf16(a1, b11, oa1, 0, 0, 0);
    }

    // offsets -> LDS transpose (wave-private rows) -> registers
    {
        float bo0 = b_off[m];
        float bo1 = (m < 2) ? b_off[16 + m] : 0.0f;
#pragma unroll
        for (int r = 0; r < 4; ++r) {
            int pp = pl_base + quad * 4 + r;
            offb[pp * 20 + m] = oa0[r] + bo0;
            if (m < 2) offb[pp * 20 + 16 + m] = oa1[r] + bo1;
        }
    }
    float oy[9], ox[9];
    {
        const int p20 = (pl_base + m) * 20;
#pragma unroll
        for (int k = 0; k < 9; ++k) {
            f32x2 o = *(const f32x2*)&offb[p20 + 2 * k];
            oy[k] = o.x; ox[k] = o.y;
        }
    }

    // ================= phase 2: deform sample (tile) + projection ==============
    f32x4 c0 = {0,0,0,0}, c1 = {0,0,0,0}, c2 = {0,0,0,0}, c3 = {0,0,0,0};
#pragma unroll
    for (int k = 0; k < 9; ++k) {
        float py = (float)(h + k / 3 - 1) + oy[k];
        float px = (float)(w + k % 3 - 1) + ox[k];
        float y0f = floorf(py), x0f = floorf(px);
        float fy = py - y0f, fx = px - x0f;
        int y0 = (int)y0f, x0i = (int)x0f;
        int y1 = y0 + 1, x1 = x0i + 1;
        bool vy0 = (y0 >= 0) & (y0 < Hh), vy1 = (y1 >= 0) & (y1 < Hh);
        bool vx0 = (x0i >= 0) & (x0i < Ww), vx1 = (x1 >= 0) & (x1 < Ww);
        float w00 = (vy0 & vx0) ? (1.0f - fy) * (1.0f - fx) : 0.0f;
        float w01 = (vy0 & vx1) ? (1.0f - fy) * fx : 0.0f;
        float w10 = (vy1 & vx0) ? fy * (1.0f - fx) : 0.0f;
        float w11 = (vy1 & vx1) ? fy * fx : 0.0f;
        int cy0 = min(max(y0, 0), Hh - 1), cy1 = min(max(y1, 0), Hh - 1);
        int cx0 = min(max(x0i, 0), Ww - 1), cx1 = min(max(x1, 0), Ww - 1);

        int r0 = cy0 - h0 + 2, r1 = cy1 - h0 + 2;      // tile coords
        int d0 = cx0 - w0 + 2, d1 = cx1 - w0 + 2;
        int inw = ((unsigned)r0 <= 7u) & ((unsigned)r1 <= 7u) &
                  ((unsigned)d0 <= 35u) & ((unsigned)d1 <= 35u);

        uint4 a00, h00, a01, h01, a10, h10, a11, h11;
        if (__all(inw)) {                              // fast path: LDS tile
            TRD(r0 * TCOLS + d0, a00, h00);
            TRD(r0 * TCOLS + d1, a01, h01);
            TRD(r1 * TCOLS + d0, a10, h10);
            TRD(r1 * TCOLS + d1, a11, h11);
        } else {                                       // rare: global gathers
            GATHF(cy0, cx0, a00, h00);
            GATHF(cy0, cx1, a01, h01);
            GATHF(cy1, cx0, a10, h10);
            GATHF(cy1, cx1, a11, h11);
        }

        uint4 o0, o1;
        o0.x = blend4(a00.x, a01.x, a10.x, a11.x, w00, w01, w10, w11);
        o0.y = blend4(a00.y, a01.y, a10.y, a11.y, w00, w01, w10, w11);
        o0.z = blend4(a00.z, a01.z, a10.z, a11.z, w00, w01, w10, w11);
        o0.w = blend4(a00.w, a01.w, a10.w, a11.w, w00, w01, w10, w11);
        o1.x = blend4(h00.x, h01.x, h10.x, h11.x, w00, w01, w10, w11);
        o1.y = blend4(h00.y, h01.y, h10.y, h11.y, w00, w01, w10, w11);
        o1.z = blend4(h00.z, h01.z, h10.z, h11.z, w00, w01, w10, w11);
        o1.w = blend4(h00.w, h01.w, h10.w, h11.w, w00, w01, w10, w11);
        bf16x8 A0 = as_bf(o0), A1 = as_bf(o1);

        const unsigned short* wf = wtbf + (size_t)(k * 8) * 512 + lane * 8;
        bf16x8 B0, B1;
        B0 = *(const bf16x8*)(wf);
        B1 = *(const bf16x8*)(wf + 512);
        c0 = __builtin_amdgcn_mfma_f32_16x16x32_bf16(A0, B0, c0, 0, 0, 0);
        c0 = __builtin_amdgcn_mfma_f32_16x16x32_bf16(A1, B1, c0, 0, 0, 0);
        B0 = *(const bf16x8*)(wf + 1024);
        B1 = *(const bf16x8*)(wf + 1536);
        c1 = __builtin_amdgcn_mfma_f32_16x16x32_bf16(A0, B0, c1, 0, 0, 0);
        c1 = __builtin_amdgcn_mfma_f32_16x16x32_bf16(A1, B1, c1, 0, 0, 0);
        B0 = *(const bf16x8*)(wf + 2048);
        B1 = *(const bf16x8*)(wf + 2560);
        c2 = __builtin_amdgcn_mfma_f32_16x16x32_bf16(A0, B0, c2, 0, 0, 0);
        c2 = __builtin_amdgcn_mfma_f32_16x16x32_bf16(A1, B1, c2, 0, 0, 0);
        B0 = *(const bf16x8*)(wf + 3072);
        B1 = *(const bf16x8*)(wf + 3584);
        c3 = __builtin_amdgcn_mfma_f32_16x16x32_bf16(A0, B0, c3, 0, 0, 0);
        c3 = __builtin_amdgcn_mfma_f32_16x16x32_bf16(A1, B1, c3, 0, 0, 0);
    }

    // ---- epilogue: BN+ReLU in regs, LDS re-layout, full-128B-line stores ----
    __syncthreads();                       // all tile reads done; reuse as obuf
    float* obuf = (float*)tile;            // [o][132] floats = 33792 B <= 36864
#pragma unroll
    for (int nt = 0; nt < 4; ++nt) {
        f32x4 a = (nt == 0) ? c0 : (nt == 1) ? c1 : (nt == 2) ? c2 : c3;
        int o = nt * 16 + m;
        float sc = scaleb[o];
        float bs = scaleb[Oo + o];
        f32x4 r;
        r[0] = fmaxf(a[0] * sc + bs, 0.0f);
        r[1] = fmaxf(a[1] * sc + bs, 0.0f);
        r[2] = fmaxf(a[2] * sc + bs, 0.0f);
        r[3] = fmaxf(a[3] * sc + bs, 0.0f);
        *(f32x4*)&obuf[o * 132 + pl_base + quad * 4] = r;
    }
    __syncthreads();
    {
        // 8 consecutive lanes = one (o, row) 128B line, fully covered per instr
        int o = t >> 3, c8 = t & 7;
        const float* src = obuf + o * 132 + c8 * 4;
        float* dst = out + ((size_t)b * Oo + o) * HW + h0 * Ww + w0 + c8 * 4;
#pragma unroll
        for (int j = 0; j < 4; ++j) {
            float4 v = *(const float4*)(src + j * 32);
            *(float4*)(dst + (size_t)j * Ww) = v;
        }
    }
}

extern "C" void kernel_launch(void* const* d_in, const int* in_sizes, int n_in,
                              void* d_out, int out_size, void* d_ws, size_t ws_size,
                              hipStream_t stream) {
    const float* x        = (const float*)d_in[0];
    const float* w_off    = (const float*)d_in[1];
    const float* b_off    = (const float*)d_in[2];
    const float* w_dcn    = (const float*)d_in[3];
    const float* b_dcn    = (const float*)d_in[4];
    const float* gamma    = (const float*)d_in[5];
    const float* beta     = (const float*)d_in[6];
    const float* run_mean = (const float*)d_in[7];
    const float* run_var  = (const float*)d_in[8];
    float* out = (float*)d_out;

    // workspace: wtbf | wofbf | scaleb
    unsigned short* wtbf  = (unsigned short*)d_ws;        // 9*8*64*8 bf16
    unsigned short* wofbf = wtbf + 9 * 8 * 64 * 8;        // 9*4*64*8 bf16
    float* scaleb         = (float*)(wofbf + 9 * 4 * 64 * 8);  // 128 floats

    prep_kernel<<<(9 * 8 * 64 * 8 + 255) / 256, 256, 0, stream>>>(
        w_dcn, b_dcn, w_off, gamma, beta, run_mean, run_var, wtbf, wofbf, scaleb);

    dcn_kernel<<<NPIX / 128, 512, 0, stream>>>(x, wtbf, wofbf, b_off, scaleb, out);
}

// Round 10
// 195.624 us; speedup vs baseline: 1.4818x; 1.0315x over previous
//
#include <hip/hip_runtime.h>

#define Hh 160
#define Ww 160
#define HW 25600
#define Bb 8
#define Cc 64
#define Oo 64
#define NPIX (Bb * HW)   // 204800

#define TROWS 8
#define TCOLS 36
#define TPIX (TROWS * TCOLS)   // 288 pixel-rows in the LDS tile

typedef __bf16 bf16x8 __attribute__((ext_vector_type(8)));
typedef float  f32x4  __attribute__((ext_vector_type(4)));
typedef float  f32x2  __attribute__((ext_vector_type(2)));

__device__ inline unsigned rnd_bf(float a) {
    unsigned u = __float_as_uint(a);
    return (u + 0x7FFFu + ((u >> 16) & 1u)) >> 16;   // RNE f32->bf16 (prep only)
}
// RNE pack of two f32 -> packed bf16x2 in ONE instruction (lo = a, hi = b)
__device__ inline unsigned cvtpk(float a, float b) {
    unsigned r;
    asm("v_cvt_pk_bf16_f32 %0, %1, %2" : "=v"(r) : "v"(a), "v"(b));
    return r;
}
__device__ inline f32x2 up2(unsigned u) {
    f32x2 r;
    r.x = __uint_as_float(u << 16);
    r.y = __uint_as_float(u & 0xffff0000u);
    return r;
}
__device__ inline unsigned blend4(unsigned u00, unsigned u01, unsigned u10, unsigned u11,
                                  float w00, float w01, float w10, float w11) {
    f32x2 r = up2(u00) * w00 + up2(u01) * w01 + up2(u10) * w10 + up2(u11) * w11;
    return cvtpk(r.x, r.y);
}
union UV { uint4 u; bf16x8 v; };
__device__ inline bf16x8 as_bf(uint4 u) { UV c; c.u = u; return c.v; }

// ---- prep: fragment-major weights so dcn's B-loads are contiguous 1KB/wave ----
__global__ __launch_bounds__(256) void prep_kernel(
    const float* __restrict__ w_dcn, const float* __restrict__ b_dcn,
    const float* __restrict__ w_off,
    const float* __restrict__ gamma, const float* __restrict__ beta,
    const float* __restrict__ run_mean, const float* __restrict__ run_var,
    unsigned short* __restrict__ wtbf, unsigned short* __restrict__ wofbf,
    float* __restrict__ scaleb)
{
    int i = blockIdx.x * 256 + threadIdx.x;
    if (i < 9 * 8 * 64 * 8) {              // 36864
        int j = i & 7, l = (i >> 3) & 63, f = (i >> 9) & 7, k = i >> 12;
        int o  = ((f >> 1) << 4) | (l & 15);
        int cc = ((l >> 4) << 3) + ((f & 1) << 5) + j;
        wtbf[i] = (unsigned short)rnd_bf(w_dcn[(o * Cc + cc) * 9 + k]);
    }
    if (i < 9 * 4 * 64 * 8) {              // 18432
        int j = i & 7, l = (i >> 3) & 63, f = (i >> 9) & 3, k = i >> 11;
        int o  = ((f >> 1) << 4) | (l & 15);
        int cc = ((l >> 4) << 3) + ((f & 1) << 5) + j;
        float v = (o < 18) ? w_off[(o * Cc + cc) * 9 + k] : 0.0f;
        wofbf[i] = (unsigned short)rnd_bf(v);
    }
    if (i < Oo) {
        float inv = gamma[i] * rsqrtf(run_var[i] + 1e-5f);
        scaleb[i]      = inv;
        scaleb[Oo + i] = b_dcn[i] * inv + (beta[i] - run_mean[i] * inv);
    }
}

// swizzled tile read: pixel-row PIX, this lane's two 16B chunks (quad, quad+4)
#define TRD(PIX, LO, HI) do {                                                  \
    int _pp = (PIX);                                                           \
    int _s  = _pp & 7;                                                         \
    const char* _tb = (const char*)tile + _pp * 128;                           \
    LO = *(const uint4*)(_tb + ((quad ^ _s) << 4));                            \
    HI = *(const uint4*)(_tb + (((quad + 4) ^ _s) << 4));                      \
} while (0)

// rare out-of-window gather straight from NCHW x (same RNE conversion as tile)
#define GATHF(CY, CX, A, H) do {                                               \
    const float* _sp = xbf + (size_t)(quad * 8) * HW + ((CY) * Ww + (CX));     \
    A = make_uint4(cvtpk(_sp[0],      _sp[HW]),                                \
                   cvtpk(_sp[2 * HW], _sp[3 * HW]),                            \
                   cvtpk(_sp[4 * HW], _sp[5 * HW]),                            \
                   cvtpk(_sp[6 * HW], _sp[7 * HW]));                           \
    const float* _hp = _sp + (size_t)32 * HW;                                  \
    H = make_uint4(cvtpk(_hp[0],      _hp[HW]),                                \
                   cvtpk(_hp[2 * HW], _hp[3 * HW]),                            \
                   cvtpk(_hp[4 * HW], _hp[5 * HW]),                            \
                   cvtpk(_hp[6 * HW], _hp[7 * HW]));                           \
} while (0)

// ---- fused: offset-conv(MFMA) + deform-sample + projection(MFMA) + BN + ReLU --
// v10 = v9 + v8's offb-elimination, at the SAFE launch bound.
// Phase-1 uses the operand-swap trick: A and B fragments of mfma_16x16x32 have
// identical lane layouts, so mfma(weights, pixels, acc) flips the accumulator
// to D[o=quad*4+r][px=m] — each lane holds offset channels of ITS OWN pixel;
// the 18 offsets are gathered with 18 compile-time __shfl's. offb LDS deleted:
// LDS = tile only (36864 B) -> 4 blocks/CU = 32-wave cap (was 24 at 47104).
// v8 proved this structure correct; its regression was solely the (512,8)
// bound capping the unified VGPR+AGPR file at 64/wave (scratch spill, +300 MB
// HBM). (512,6) is the bound v9 runs spill-free at — kept here.
__global__ __launch_bounds__(512, 6) void dcn_kernel(
    const float* __restrict__ x,
    const unsigned short* __restrict__ wtbf,    // [9][8][64][8]
    const unsigned short* __restrict__ wofbf,   // [9][4][64][8]
    const float* __restrict__ b_off,
    const float* __restrict__ scaleb,
    float* __restrict__ out)
{
    __shared__ __align__(16) unsigned short tile[TPIX * 64];  // 36864 B total

    const int t = threadIdx.x;
    const int lane = t & 63, wv = t >> 6;      // wv 0..7
    const int m = lane & 15, quad = lane >> 4;

    int blk = blockIdx.x;                      // 1600
    int b   = blk & 7;                         // XCD swizzle: 1 image/XCD
    int nb  = blk >> 3;                        // 0..199
    int h0  = (nb / 5) * 4;                    // 4-row group
    int w0  = (nb % 5) * 32;                   // 32-px segment, row-aligned

    const int rloc  = wv >> 1;                 // wave's output row (0..3)
    const int chalf = (wv & 1) * 16;           // wave's col half
    const int h = h0 + rloc;
    const int w = w0 + chalf + m;              // this lane's pixel col
    const int pl_base = rloc * 32 + chalf;     // wave's first pixel id (0..127)

    const float* xbf = x + (size_t)b * Cc * HW;

    // ---- stage tile from NCHW x: transpose + bf16 pack, coalesced along w ----
#pragma unroll
    for (int it = 0; it < 18; ++it) {
        int id  = t + it * 512;
        int col = id % 36;
        int rr  = id / 36;                 // c2*8 + r
        int r   = rr & 7;
        int c2  = rr >> 3;                 // channel pair 0..31
        int yr = min(max(h0 - 2 + r, 0), Hh - 1);
        int xc = min(max(w0 - 2 + col, 0), Ww - 1);
        const float* sp = xbf + (size_t)(c2 * 2) * HW + (yr * Ww + xc);
        unsigned v = cvtpk(sp[0], sp[HW]);
        int pix = r * TCOLS + col;
        *(unsigned*)((char*)tile + pix * 128
                     + ((((c2 >> 2) ^ (pix & 7)) << 4) + ((c2 & 3) << 2))) = v;
    }
    __syncthreads();

    // ===== phase 1: offset conv, SWAPPED operands: D[o=quad*4+r][px=m] ========
    f32x4 oa0 = {0,0,0,0}, oa1 = {0,0,0,0};
#pragma unroll
    for (int k = 0; k < 9; ++k) {
        int hp = h + k / 3 - 1, wp = w + (k % 3) - 1;
        bool ok = (hp >= 0) & (hp < Hh) & (wp >= 0) & (wp < Ww);
        int r = min(max(hp, 0), Hh - 1) - h0 + 2;      // in [0,7]
        int c = min(max(wp, 0), Ww - 1) - w0 + 2;      // in [0,35]
        uint4 r0, r1;
        TRD(r * TCOLS + c, r0, r1);
        if (!ok) { r0 = make_uint4(0,0,0,0); r1 = make_uint4(0,0,0,0); }
        bf16x8 a0 = as_bf(r0), a1 = as_bf(r1);

        const unsigned short* wf = wofbf + (size_t)(k * 4) * 512 + lane * 8;
        bf16x8 b00 = *(const bf16x8*)(wf);
        bf16x8 b01 = *(const bf16x8*)(wf + 512);
        bf16x8 b10 = *(const bf16x8*)(wf + 1024);
        bf16x8 b11 = *(const bf16x8*)(wf + 1536);
        // weights as A-operand, pixels as B-operand (fragments layout-identical)
        oa0 = __builtin_amdgcn_mfma_f32_16x16x32_bf16(b00, a0, oa0, 0, 0, 0);
        oa0 = __builtin_amdgcn_mfma_f32_16x16x32_bf16(b01, a1, oa0, 0, 0, 0);
        oa1 = __builtin_amdgcn_mfma_f32_16x16x32_bf16(b10, a0, oa1, 0, 0, 0);
        oa1 = __builtin_amdgcn_mfma_f32_16x16x32_bf16(b11, a1, oa1, 0, 0, 0);
    }

    // offsets: lane (m,quad) holds ch quad*4+r (oa0) / 16+quad*4+r (oa1) of
    // pixel m. Gather all 18 channels of OWN pixel via compile-time shuffles.
    float oy[9], ox[9];
#pragma unroll
    for (int k = 0; k < 9; ++k) {
        int cy = 2 * k, cx = 2 * k + 1;
        float vy = (cy < 16) ? __shfl(oa0[cy & 3], ((cy >> 2) << 4) + m, 64)
                             : __shfl(oa1[(cy - 16) & 3], (((cy - 16) >> 2) << 4) + m, 64);
        float vx = (cx < 16) ? __shfl(oa0[cx & 3], ((cx >> 2) << 4) + m, 64)
                             : __shfl(oa1[(cx - 16) & 3], (((cx - 16) >> 2) << 4) + m, 64);
        oy[k] = vy + b_off[cy];
        ox[k] = vx + b_off[cx];
    }

    // ================= phase 2: deform sample (tile) + projection ==============
    f32x4 c0 = {0,0,0,0}, c1 = {0,0,0,0}, c2 = {0,0,0,0}, c3 = {0,0,0,0};
#pragma unroll
    for (int k = 0; k < 9; ++k) {
        float py = (float)(h + k / 3 - 1) + oy[k];
        float px = (float)(w + k % 3 - 1) + ox[k];
        float y0f = floorf(py), x0f = floorf(px);
        float fy = py - y0f, fx = px - x0f;
        int y0 = (int)y0f, x0i = (int)x0f;
        int y1 = y0 + 1, x1 = x0i + 1;
        bool vy0 = (y0 >= 0) & (y0 < Hh), vy1 = (y1 >= 0) & (y1 < Hh);
        bool vx0 = (x0i >= 0) & (x0i < Ww), vx1 = (x1 >= 0) & (x1 < Ww);
        float w00 = (vy0 & vx0) ? (1.0f - fy) * (1.0f - fx) : 0.0f;
        float w01 = (vy0 & vx1) ? (1.0f - fy) * fx : 0.0f;
        float w10 = (vy1 & vx0) ? fy * (1.0f - fx) : 0.0f;
        float w11 = (vy1 & vx1) ? fy * fx : 0.0f;
        int cy0 = min(max(y0, 0), Hh - 1), cy1 = min(max(y1, 0), Hh - 1);
        int cx0 = min(max(x0i, 0), Ww - 1), cx1 = min(max(x1, 0), Ww - 1);

        int r0 = cy0 - h0 + 2, r1 = cy1 - h0 + 2;      // tile coords
        int d0 = cx0 - w0 + 2, d1 = cx1 - w0 + 2;
        int inw = ((unsigned)r0 <= 7u) & ((unsigned)r1 <= 7u) &
                  ((unsigned)d0 <= 35u) & ((unsigned)d1 <= 35u);

        uint4 a00, h00, a01, h01, a10, h10, a11, h11;
        if (__all(inw)) {                              // fast path: LDS tile
            TRD(r0 * TCOLS + d0, a00, h00);
            TRD(r0 * TCOLS + d1, a01, h01);
            TRD(r1 * TCOLS + d0, a10, h10);
            TRD(r1 * TCOLS + d1, a11, h11);
        } else {                                       // rare: global gathers
            GATHF(cy0, cx0, a00, h00);
            GATHF(cy0, cx1, a01, h01);
            GATHF(cy1, cx0, a10, h10);
            GATHF(cy1, cx1, a11, h11);
        }

        uint4 o0, o1;
        o0.x = blend4(a00.x, a01.x, a10.x, a11.x, w00, w01, w10, w11);
        o0.y = blend4(a00.y, a01.y, a10.y, a11.y, w00, w01, w10, w11);
        o0.z = blend4(a00.z, a01.z, a10.z, a11.z, w00, w01, w10, w11);
        o0.w = blend4(a00.w, a01.w, a10.w, a11.w, w00, w01, w10, w11);
        o1.x = blend4(h00.x, h01.x, h10.x, h11.x, w00, w01, w10, w11);
        o1.y = blend4(h00.y, h01.y, h10.y, h11.y, w00, w01, w10, w11);
        o1.z = blend4(h00.z, h01.z, h10.z, h11.z, w00, w01, w10, w11);
        o1.w = blend4(h00.w, h01.w, h10.w, h11.w, w00, w01, w10, w11);
        bf16x8 A0 = as_bf(o0), A1 = as_bf(o1);

        const unsigned short* wf = wtbf + (size_t)(k * 8) * 512 + lane * 8;
        bf16x8 B0, B1;
        B0 = *(const bf16x8*)(wf);
        B1 = *(const bf16x8*)(wf + 512);
        c0 = __builtin_amdgcn_mfma_f32_16x16x32_bf16(A0, B0, c0, 0, 0, 0);
        c0 = __builtin_amdgcn_mfma_f32_16x16x32_bf16(A1, B1, c0, 0, 0, 0);
        B0 = *(const bf16x8*)(wf + 1024);
        B1 = *(const bf16x8*)(wf + 1536);
        c1 = __builtin_amdgcn_mfma_f32_16x16x32_bf16(A0, B0, c1, 0, 0, 0);
        c1 = __builtin_amdgcn_mfma_f32_16x16x32_bf16(A1, B1, c1, 0, 0, 0);
        B0 = *(const bf16x8*)(wf + 2048);
        B1 = *(const bf16x8*)(wf + 2560);
        c2 = __builtin_amdgcn_mfma_f32_16x16x32_bf16(A0, B0, c2, 0, 0, 0);
        c2 = __builtin_amdgcn_mfma_f32_16x16x32_bf16(A1, B1, c2, 0, 0, 0);
        B0 = *(const bf16x8*)(wf + 3072);
        B1 = *(const bf16x8*)(wf + 3584);
        c3 = __builtin_amdgcn_mfma_f32_16x16x32_bf16(A0, B0, c3, 0, 0, 0);
        c3 = __builtin_amdgcn_mfma_f32_16x16x32_bf16(A1, B1, c3, 0, 0, 0);
    }

    // ---- epilogue: BN+ReLU in regs, LDS re-layout, full-128B-line stores ----
    __syncthreads();                       // all tile reads done; reuse as obuf
    float* obuf = (float*)tile;            // [o][132] floats = 33792 B <= 36864
#pragma unroll
    for (int nt = 0; nt < 4; ++nt) {
        f32x4 a = (nt == 0) ? c0 : (nt == 1) ? c1 : (nt == 2) ? c2 : c3;
        int o = nt * 16 + m;
        float sc = scaleb[o];
        float bs = scaleb[Oo + o];
        f32x4 r;
        r[0] = fmaxf(a[0] * sc + bs, 0.0f);
        r[1] = fmaxf(a[1] * sc + bs, 0.0f);
        r[2] = fmaxf(a[2] * sc + bs, 0.0f);
        r[3] = fmaxf(a[3] * sc + bs, 0.0f);
        *(f32x4*)&obuf[o * 132 + pl_base + quad * 4] = r;
    }
    __syncthreads();
    {
        // 8 consecutive lanes = one (o, row) 128B line, fully covered per instr
        int o = t >> 3, c8 = t & 7;
        const float* src = obuf + o * 132 + c8 * 4;
        float* dst = out + ((size_t)b * Oo + o) * HW + h0 * Ww + w0 + c8 * 4;
#pragma unroll
        for (int j = 0; j < 4; ++j) {
            float4 v = *(const float4*)(src + j * 32);
            *(float4*)(dst + (size_t)j * Ww) = v;
        }
    }
}

extern "C" void kernel_launch(void* const* d_in, const int* in_sizes, int n_in,
                              void* d_out, int out_size, void* d_ws, size_t ws_size,
                              hipStream_t stream) {
    const float* x        = (const float*)d_in[0];
    const float* w_off    = (const float*)d_in[1];
    const float* b_off    = (const float*)d_in[2];
    const float* w_dcn    = (const float*)d_in[3];
    const float* b_dcn    = (const float*)d_in[4];
    const float* gamma    = (const float*)d_in[5];
    const float* beta     = (const float*)d_in[6];
    const float* run_mean = (const float*)d_in[7];
    const float* run_var  = (const float*)d_in[8];
    float* out = (float*)d_out;

    // workspace: wtbf | wofbf | scaleb
    unsigned short* wtbf  = (unsigned short*)d_ws;        // 9*8*64*8 bf16
    unsigned short* wofbf = wtbf + 9 * 8 * 64 * 8;        // 9*4*64*8 bf16
    float* scaleb         = (float*)(wofbf + 9 * 4 * 64 * 8);  // 128 floats

    prep_kernel<<<(9 * 8 * 64 * 8 + 255) / 256, 256, 0, stream>>>(
        w_dcn, b_dcn, w_off, gamma, beta, run_mean, run_var, wtbf, wofbf, scaleb);

    dcn_kernel<<<NPIX / 128, 512, 0, stream>>>(x, wtbf, wofbf, b_off, scaleb, out);
}

// Round 11
// 189.429 us; speedup vs baseline: 1.5302x; 1.0327x over previous
//
#include <hip/hip_runtime.h>

#define Hh 160
#define Ww 160
#define HW 25600
#define Bb 8
#define Cc 64
#define Oo 64
#define NPIX (Bb * HW)   // 204800

#define TROWS 8
#define TCOLS 36
#define TPIX (TROWS * TCOLS)   // 288 pixel-rows in the LDS tile

typedef __bf16 bf16x8 __attribute__((ext_vector_type(8)));
typedef float  f32x4  __attribute__((ext_vector_type(4)));
typedef float  f32x2  __attribute__((ext_vector_type(2)));

__device__ inline unsigned rnd_bf(float a) {
    unsigned u = __float_as_uint(a);
    return (u + 0x7FFFu + ((u >> 16) & 1u)) >> 16;   // RNE f32->bf16 (prep only)
}
// RNE pack of two f32 -> packed bf16x2 in ONE instruction (lo = a, hi = b)
__device__ inline unsigned cvtpk(float a, float b) {
    unsigned r;
    asm("v_cvt_pk_bf16_f32 %0, %1, %2" : "=v"(r) : "v"(a), "v"(b));
    return r;
}
__device__ inline f32x2 up2(unsigned u) {
    f32x2 r;
    r.x = __uint_as_float(u << 16);
    r.y = __uint_as_float(u & 0xffff0000u);
    return r;
}
__device__ inline unsigned blend4(unsigned u00, unsigned u01, unsigned u10, unsigned u11,
                                  float w00, float w01, float w10, float w11) {
    f32x2 r = up2(u00) * w00 + up2(u01) * w01 + up2(u10) * w10 + up2(u11) * w11;
    return cvtpk(r.x, r.y);
}
union UV { uint4 u; bf16x8 v; };
__device__ inline bf16x8 as_bf(uint4 u) { UV c; c.u = u; return c.v; }

// ---- prep: fragment-major weights so dcn's B-loads are contiguous 1KB/wave ----
__global__ __launch_bounds__(256) void prep_kernel(
    const float* __restrict__ w_dcn, const float* __restrict__ b_dcn,
    const float* __restrict__ w_off,
    const float* __restrict__ gamma, const float* __restrict__ beta,
    const float* __restrict__ run_mean, const float* __restrict__ run_var,
    unsigned short* __restrict__ wtbf, unsigned short* __restrict__ wofbf,
    float* __restrict__ scaleb)
{
    int i = blockIdx.x * 256 + threadIdx.x;
    if (i < 9 * 8 * 64 * 8) {              // 36864
        int j = i & 7, l = (i >> 3) & 63, f = (i >> 9) & 7, k = i >> 12;
        int o  = ((f >> 1) << 4) | (l & 15);
        int cc = ((l >> 4) << 3) + ((f & 1) << 5) + j;
        wtbf[i] = (unsigned short)rnd_bf(w_dcn[(o * Cc + cc) * 9 + k]);
    }
    if (i < 9 * 4 * 64 * 8) {              // 18432
        int j = i & 7, l = (i >> 3) & 63, f = (i >> 9) & 3, k = i >> 11;
        int o  = ((f >> 1) << 4) | (l & 15);
        int cc = ((l >> 4) << 3) + ((f & 1) << 5) + j;
        float v = (o < 18) ? w_off[(o * Cc + cc) * 9 + k] : 0.0f;
        wofbf[i] = (unsigned short)rnd_bf(v);
    }
    if (i < Oo) {
        float inv = gamma[i] * rsqrtf(run_var[i] + 1e-5f);
        scaleb[i]      = inv;
        scaleb[Oo + i] = b_dcn[i] * inv + (beta[i] - run_mean[i] * inv);
    }
}

// swizzled tile read: pixel-row PIX, this lane's two 16B chunks (quad, quad+4)
#define TRD(PIX, LO, HI) do {                                                  \
    int _pp = (PIX);                                                           \
    int _s  = _pp & 7;                                                         \
    const char* _tb = (const char*)tile + _pp * 128;                           \
    LO = *(const uint4*)(_tb + ((quad ^ _s) << 4));                            \
    HI = *(const uint4*)(_tb + (((quad + 4) ^ _s) << 4));                      \
} while (0)

// rare out-of-window gather straight from NCHW x (same RNE conversion as tile)
#define GATHF(CY, CX, A, H) do {                                               \
    const float* _sp = xbf + (size_t)(quad * 8) * HW + ((CY) * Ww + (CX));     \
    A = make_uint4(cvtpk(_sp[0],      _sp[HW]),                                \
                   cvtpk(_sp[2 * HW], _sp[3 * HW]),                            \
                   cvtpk(_sp[4 * HW], _sp[5 * HW]),                            \
                   cvtpk(_sp[6 * HW], _sp[7 * HW]));                           \
    const float* _hp = _sp + (size_t)32 * HW;                                  \
    H = make_uint4(cvtpk(_hp[0],      _hp[HW]),                                \
                   cvtpk(_hp[2 * HW], _hp[3 * HW]),                            \
                   cvtpk(_hp[4 * HW], _hp[5 * HW]),                            \
                   cvtpk(_hp[6 * HW], _hp[7 * HW]));                           \
} while (0)

// gather buffer: 8 raw uint4 (4 corners x lo/hi) + 4 bilinear weights.
// All indices compile-time (Ga/Gb alternated explicitly) -> stays in registers.
struct GBuf { uint4 g[8]; float w[4]; };

// ---- fused: offset-conv(MFMA) + deform-sample + projection(MFMA) + BN + ReLU --
// v11 = v10 + explicit software pipeline in phase 2, funded by (512,4).
// Occupancy is register-capped at 2 blocks/CU (16 waves) regardless of bound
// (total VGPR+AGPR > 64), so raising the reg cap 85->128 costs NO residency.
// ISSUE(k+1) (coords + weights + 16 ds_read_b128 into the other GBuf) is
// issued BEFORE MATH(k)'s blends/MFMAs: in-order LDS returns mean the counted
// lgkmcnt for tap k doesn't drain tap k+1's reads -> LDS latency and the read
// burst hide under blend VALU, overlapping the two pipes that the profile
// shows are each ~50% busy but serialized. oy/ox arrays deleted (-18 regs);
// the 2 offset shuffles per tap moved into ISSUE (oa0/oa1 stay in AGPRs).
__global__ __launch_bounds__(512, 4) void dcn_kernel(
    const float* __restrict__ x,
    const unsigned short* __restrict__ wtbf,    // [9][8][64][8]
    const unsigned short* __restrict__ wofbf,   // [9][4][64][8]
    const float* __restrict__ b_off,
    const float* __restrict__ scaleb,
    float* __restrict__ out)
{
    __shared__ __align__(16) unsigned short tile[TPIX * 64];  // 36864 B total

    const int t = threadIdx.x;
    const int lane = t & 63, wv = t >> 6;      // wv 0..7
    const int m = lane & 15, quad = lane >> 4;

    int blk = blockIdx.x;                      // 1600
    int b   = blk & 7;                         // XCD swizzle: 1 image/XCD
    int nb  = blk >> 3;                        // 0..199
    int h0  = (nb / 5) * 4;                    // 4-row group
    int w0  = (nb % 5) * 32;                   // 32-px segment, row-aligned

    const int rloc  = wv >> 1;                 // wave's output row (0..3)
    const int chalf = (wv & 1) * 16;           // wave's col half
    const int h = h0 + rloc;
    const int w = w0 + chalf + m;              // this lane's pixel col
    const int pl_base = rloc * 32 + chalf;     // wave's first pixel id (0..127)

    const float* xbf = x + (size_t)b * Cc * HW;

    // ---- stage tile from NCHW x: transpose + bf16 pack, coalesced along w ----
#pragma unroll
    for (int it = 0; it < 18; ++it) {
        int id  = t + it * 512;
        int col = id % 36;
        int rr  = id / 36;                 // c2*8 + r
        int r   = rr & 7;
        int c2  = rr >> 3;                 // channel pair 0..31
        int yr = min(max(h0 - 2 + r, 0), Hh - 1);
        int xc = min(max(w0 - 2 + col, 0), Ww - 1);
        const float* sp = xbf + (size_t)(c2 * 2) * HW + (yr * Ww + xc);
        unsigned v = cvtpk(sp[0], sp[HW]);
        int pix = r * TCOLS + col;
        *(unsigned*)((char*)tile + pix * 128
                     + ((((c2 >> 2) ^ (pix & 7)) << 4) + ((c2 & 3) << 2))) = v;
    }
    __syncthreads();

    // ===== phase 1: offset conv, SWAPPED operands: D[o=quad*4+r][px=m] ========
    f32x4 oa0 = {0,0,0,0}, oa1 = {0,0,0,0};
#pragma unroll
    for (int k = 0; k < 9; ++k) {
        int hp = h + k / 3 - 1, wp = w + (k % 3) - 1;
        bool ok = (hp >= 0) & (hp < Hh) & (wp >= 0) & (wp < Ww);
        int r = min(max(hp, 0), Hh - 1) - h0 + 2;      // in [0,7]
        int c = min(max(wp, 0), Ww - 1) - w0 + 2;      // in [0,35]
        uint4 r0, r1;
        TRD(r * TCOLS + c, r0, r1);
        if (!ok) { r0 = make_uint4(0,0,0,0); r1 = make_uint4(0,0,0,0); }
        bf16x8 a0 = as_bf(r0), a1 = as_bf(r1);

        const unsigned short* wf = wofbf + (size_t)(k * 4) * 512 + lane * 8;
        bf16x8 b00 = *(const bf16x8*)(wf);
        bf16x8 b01 = *(const bf16x8*)(wf + 512);
        bf16x8 b10 = *(const bf16x8*)(wf + 1024);
        bf16x8 b11 = *(const bf16x8*)(wf + 1536);
        // weights as A-operand, pixels as B-operand (fragments layout-identical)
        oa0 = __builtin_amdgcn_mfma_f32_16x16x32_bf16(b00, a0, oa0, 0, 0, 0);
        oa0 = __builtin_amdgcn_mfma_f32_16x16x32_bf16(b01, a1, oa0, 0, 0, 0);
        oa1 = __builtin_amdgcn_mfma_f32_16x16x32_bf16(b10, a0, oa1, 0, 0, 0);
        oa1 = __builtin_amdgcn_mfma_f32_16x16x32_bf16(b11, a1, oa1, 0, 0, 0);
    }

    // ================= phase 2: pipelined deform sample + projection ===========
    f32x4 c0 = {0,0,0,0}, c1 = {0,0,0,0}, c2 = {0,0,0,0}, c3 = {0,0,0,0};

    // per-tap offset fetch: lane (m,quad) holds ch quad*4+r of pixel m (oa);
    // gather own pixel's channel via compile-time-structured shuffle.
#define OFFCH(C) ((C) < 16 ? __shfl(oa0[(C) & 3], (((C) >> 2) << 4) + m, 64)   \
                           : __shfl(oa1[((C) - 16) & 3],                       \
                                    ((((C) - 16) >> 2) << 4) + m, 64))

#define ISSUE(K, X) do {                                                       \
    float _oy = OFFCH(2 * (K))     + b_off[2 * (K)];                           \
    float _ox = OFFCH(2 * (K) + 1) + b_off[2 * (K) + 1];                       \
    float _py = (float)(h + (K) / 3 - 1) + _oy;                                \
    float _px = (float)(w + (K) % 3 - 1) + _ox;                                \
    float _y0f = floorf(_py), _x0f = floorf(_px);                              \
    float _fy = _py - _y0f, _fx = _px - _x0f;                                  \
    int _y0 = (int)_y0f, _x0 = (int)_x0f;                                      \
    int _y1 = _y0 + 1, _x1 = _x0 + 1;                                          \
    bool _vy0 = (_y0 >= 0) & (_y0 < Hh), _vy1 = (_y1 >= 0) & (_y1 < Hh);       \
    bool _vx0 = (_x0 >= 0) & (_x0 < Ww), _vx1 = (_x1 >= 0) & (_x1 < Ww);       \
    X.w[0] = (_vy0 & _vx0) ? (1.0f - _fy) * (1.0f - _fx) : 0.0f;               \
    X.w[1] = (_vy0 & _vx1) ? (1.0f - _fy) * _fx : 0.0f;                        \
    X.w[2] = (_vy1 & _vx0) ? _fy * (1.0f - _fx) : 0.0f;                        \
    X.w[3] = (_vy1 & _vx1) ? _fy * _fx : 0.0f;                                 \
    int _cy0 = min(max(_y0, 0), Hh - 1), _cy1 = min(max(_y1, 0), Hh - 1);      \
    int _cx0 = min(max(_x0, 0), Ww - 1), _cx1 = min(max(_x1, 0), Ww - 1);      \
    int _r0 = _cy0 - h0 + 2, _r1 = _cy1 - h0 + 2;                              \
    int _d0 = _cx0 - w0 + 2, _d1 = _cx1 - w0 + 2;                              \
    int _inw = ((unsigned)_r0 <= 7u) & ((unsigned)_r1 <= 7u) &                 \
               ((unsigned)_d0 <= 35u) & ((unsigned)_d1 <= 35u);                \
    if (__all(_inw)) {                                                         \
        TRD(_r0 * TCOLS + _d0, X.g[0], X.g[1]);                                \
        TRD(_r0 * TCOLS + _d1, X.g[2], X.g[3]);                                \
        TRD(_r1 * TCOLS + _d0, X.g[4], X.g[5]);                                \
        TRD(_r1 * TCOLS + _d1, X.g[6], X.g[7]);                                \
    } else {                                                                   \
        GATHF(_cy0, _cx0, X.g[0], X.g[1]);                                     \
        GATHF(_cy0, _cx1, X.g[2], X.g[3]);                                     \
        GATHF(_cy1, _cx0, X.g[4], X.g[5]);                                     \
        GATHF(_cy1, _cx1, X.g[6], X.g[7]);                                     \
    }                                                                          \
} while (0)

#define MATH(K, X) do {                                                        \
    uint4 _o0, _o1;                                                            \
    _o0.x = blend4(X.g[0].x, X.g[2].x, X.g[4].x, X.g[6].x,                     \
                   X.w[0], X.w[1], X.w[2], X.w[3]);                            \
    _o0.y = blend4(X.g[0].y, X.g[2].y, X.g[4].y, X.g[6].y,                     \
                   X.w[0], X.w[1], X.w[2], X.w[3]);                            \
    _o0.z = blend4(X.g[0].z, X.g[2].z, X.g[4].z, X.g[6].z,                     \
                   X.w[0], X.w[1], X.w[2], X.w[3]);                            \
    _o0.w = blend4(X.g[0].w, X.g[2].w, X.g[4].w, X.g[6].w,                     \
                   X.w[0], X.w[1], X.w[2], X.w[3]);                            \
    _o1.x = blend4(X.g[1].x, X.g[3].x, X.g[5].x, X.g[7].x,                     \
                   X.w[0], X.w[1], X.w[2], X.w[3]);                            \
    _o1.y = blend4(X.g[1].y, X.g[3].y, X.g[5].y, X.g[7].y,                     \
                   X.w[0], X.w[1], X.w[2], X.w[3]);                            \
    _o1.z = blend4(X.g[1].z, X.g[3].z, X.g[5].z, X.g[7].z,                     \
                   X.w[0], X.w[1], X.w[2], X.w[3]);                            \
    _o1.w = blend4(X.g[1].w, X.g[3].w, X.g[5].w, X.g[7].w,                     \
                   X.w[0], X.w[1], X.w[2], X.w[3]);                            \
    bf16x8 _A0 = as_bf(_o0), _A1 = as_bf(_o1);                                 \
    const unsigned short* _wf = wtbf + (size_t)((K) * 8) * 512 + lane * 8;     \
    bf16x8 _B0, _B1;                                                           \
    _B0 = *(const bf16x8*)(_wf);                                               \
    _B1 = *(const bf16x8*)(_wf + 512);                                         \
    c0 = __builtin_amdgcn_mfma_f32_16x16x32_bf16(_A0, _B0, c0, 0, 0, 0);       \
    c0 = __builtin_amdgcn_mfma_f32_16x16x32_bf16(_A1, _B1, c0, 0, 0, 0);       \
    _B0 = *(const bf16x8*)(_wf + 1024);                                        \
    _B1 = *(const bf16x8*)(_wf + 1536);                                        \
    c1 = __builtin_amdgcn_mfma_f32_16x16x32_bf16(_A0, _B0, c1, 0, 0, 0);       \
    c1 = __builtin_amdgcn_mfma_f32_16x16x32_bf16(_A1, _B1, c1, 0, 0, 0);       \
    _B0 = *(const bf16x8*)(_wf + 2048);                                        \
    _B1 = *(const bf16x8*)(_wf + 2560);                                        \
    c2 = __builtin_amdgcn_mfma_f32_16x16x32_bf16(_A0, _B0, c2, 0, 0, 0);       \
    c2 = __builtin_amdgcn_mfma_f32_16x16x32_bf16(_A1, _B1, c2, 0, 0, 0);       \
    _B0 = *(const bf16x8*)(_wf + 3072);                                        \
    _B1 = *(const bf16x8*)(_wf + 3584);                                        \
    c3 = __builtin_amdgcn_mfma_f32_16x16x32_bf16(_A0, _B0, c3, 0, 0, 0);       \
    c3 = __builtin_amdgcn_mfma_f32_16x16x32_bf16(_A1, _B1, c3, 0, 0, 0);       \
} while (0)

    GBuf Ga, Gb;
    ISSUE(0, Ga);
    ISSUE(1, Gb); MATH(0, Ga);
    ISSUE(2, Ga); MATH(1, Gb);
    ISSUE(3, Gb); MATH(2, Ga);
    ISSUE(4, Ga); MATH(3, Gb);
    ISSUE(5, Gb); MATH(4, Ga);
    ISSUE(6, Ga); MATH(5, Gb);
    ISSUE(7, Gb); MATH(6, Ga);
    ISSUE(8, Ga); MATH(7, Gb);
    MATH(8, Ga);

#undef MATH
#undef ISSUE
#undef OFFCH

    // ---- epilogue: BN+ReLU in regs, LDS re-layout, full-128B-line stores ----
    __syncthreads();                       // all tile reads done; reuse as obuf
    float* obuf = (float*)tile;            // [o][132] floats = 33792 B <= 36864
#pragma unroll
    for (int nt = 0; nt < 4; ++nt) {
        f32x4 a = (nt == 0) ? c0 : (nt == 1) ? c1 : (nt == 2) ? c2 : c3;
        int o = nt * 16 + m;
        float sc = scaleb[o];
        float bs = scaleb[Oo + o];
        f32x4 r;
        r[0] = fmaxf(a[0] * sc + bs, 0.0f);
        r[1] = fmaxf(a[1] * sc + bs, 0.0f);
        r[2] = fmaxf(a[2] * sc + bs, 0.0f);
        r[3] = fmaxf(a[3] * sc + bs, 0.0f);
        *(f32x4*)&obuf[o * 132 + pl_base + quad * 4] = r;
    }
    __syncthreads();
    {
        // 8 consecutive lanes = one (o, row) 128B line, fully covered per instr
        int o = t >> 3, c8 = t & 7;
        const float* src = obuf + o * 132 + c8 * 4;
        float* dst = out + ((size_t)b * Oo + o) * HW + h0 * Ww + w0 + c8 * 4;
#pragma unroll
        for (int j = 0; j < 4; ++j) {
            float4 v = *(const float4*)(src + j * 32);
            *(float4*)(dst + (size_t)j * Ww) = v;
        }
    }
}

extern "C" void kernel_launch(void* const* d_in, const int* in_sizes, int n_in,
                              void* d_out, int out_size, void* d_ws, size_t ws_size,
                              hipStream_t stream) {
    const float* x        = (const float*)d_in[0];
    const float* w_off    = (const float*)d_in[1];
    const float* b_off    = (const float*)d_in[2];
    const float* w_dcn    = (const float*)d_in[3];
    const float* b_dcn    = (const float*)d_in[4];
    const float* gamma    = (const float*)d_in[5];
    const float* beta     = (const float*)d_in[6];
    const float* run_mean = (const float*)d_in[7];
    const float* run_var  = (const float*)d_in[8];
    float* out = (float*)d_out;

    // workspace: wtbf | wofbf | scaleb
    unsigned short* wtbf  = (unsigned short*)d_ws;        // 9*8*64*8 bf16
    unsigned short* wofbf = wtbf + 9 * 8 * 64 * 8;        // 9*4*64*8 bf16
    float* scaleb         = (float*)(wofbf + 9 * 4 * 64 * 8);  // 128 floats

    prep_kernel<<<(9 * 8 * 64 * 8 + 255) / 256, 256, 0, stream>>>(
        w_dcn, b_dcn, w_off, gamma, beta, run_mean, run_var, wtbf, wofbf, scaleb);

    dcn_kernel<<<NPIX / 128, 512, 0, stream>>>(x, wtbf, wofbf, b_off, scaleb, out);
}